// Round 2
// baseline (254.067 us; speedup 1.0000x reference)
//
#include <hip/hip_runtime.h>

// Gated delta-rule recurrent cell, single step.
// B=128, H=16, Dk=Dv=128.
//
// Round-2 structure: ZERO barriers, ZERO LDS. Each WAVE independently owns a
// 128(k) x 32(v) column-slice of one (b,h) state tile. Lane layout:
//   kgrp = lane>>3 (8 groups of 16 contiguous rows), vgrp = lane&7 (8 float4s
//   = 32 columns). Each lane loads 16 float4 of S (16 outstanding dwordx4),
// accumulates A = S^T k and Bq = S^T q partials in-register, then a 3-round
// __shfl_xor butterfly (masks 8/16/32) finishes the k-reduction inside the
// wave. delta/out computed per-lane; state rewritten from the register tile.
// Every wave is an independent load->shuffle->store stream; waves on a CU
// run phase-decoupled, keeping the memory pipe continuously fed (vs the
// previous barrier-phased version pinned at 2.5 TB/s).
//
// out[v] = decay*Bq[v] + (k.q)*delta[v]  (algebraic identity, single pass)

#define DK 128
#define DV 128
#define VS 32              // v-slice width per wave
typedef float f4 __attribute__((ext_vector_type(4)));

__global__ __launch_bounds__(256, 4) void s1_cell_kernel(
    const float* __restrict__ q,
    const float* __restrict__ k,
    const float* __restrict__ v,
    const float* __restrict__ g,
    const float* __restrict__ beta,
    const float* __restrict__ S,
    float* __restrict__ out,      // full d_out
    int BH)
{
    const int wid  = threadIdx.x >> 6;           // wave in block: 0..3
    const int lane = threadIdx.x & 63;
    const int task = (blockIdx.x << 2) + wid;    // 0 .. BH*4-1
    const int bh   = task >> 2;
    const int sl   = task & 3;                   // v-slice 0..3

    const int vgrp = lane & 7;                   // float4 column within slice
    const int kgrp = lane >> 3;                  // row group (16 rows each)
    const int colf = sl * VS + vgrp * 4;         // global column (float idx)
    const int row0 = kgrp * 16;

    const size_t stile = (size_t)bh * DK * DV;
    const float* __restrict__ Sp = S   + stile + (size_t)row0 * DV + colf;
    float* __restrict__ So = out + (size_t)BH * DV + stile + (size_t)row0 * DV + colf;

    const float decay = expf(g[bh]);
    const float bta   = beta[bh];

    // k for this lane's 16 contiguous rows (vectorized, L1-broadcast)
    f4 kt[4];
    #pragma unroll
    for (int j = 0; j < 4; ++j)
        kt[j] = *(const f4*)(k + bh * DK + row0 + 4 * j);

    const f4 vv = *(const f4*)(v + bh * DV + colf);

    // --- load S tile (16 outstanding dwordx4 per lane) ---
    f4 s[16];
    #pragma unroll
    for (int i = 0; i < 16; ++i)
        s[i] = *(const f4*)(Sp + (size_t)i * DV);

    // --- accumulate A/Bq/kq partials (q consumed on the fly, short liveness) ---
    f4 a = {0.f, 0.f, 0.f, 0.f};
    f4 b = {0.f, 0.f, 0.f, 0.f};
    float kq = 0.f;
    #pragma unroll
    for (int j = 0; j < 4; ++j) {
        const f4 qj = *(const f4*)(q + bh * DK + row0 + 4 * j);
        const f4 kj = kt[j];
        a += s[4*j+0] * kj.x;  b += s[4*j+0] * qj.x;
        a += s[4*j+1] * kj.y;  b += s[4*j+1] * qj.y;
        a += s[4*j+2] * kj.z;  b += s[4*j+2] * qj.z;
        a += s[4*j+3] * kj.w;  b += s[4*j+3] * qj.w;
        kq += kj.x*qj.x + kj.y*qj.y + kj.z*qj.z + kj.w*qj.w;
    }

    // --- butterfly reduce over the 8 kgrps (lane-bit masks 8,16,32) ---
    #pragma unroll
    for (int m = 8; m <= 32; m <<= 1) {
        a.x += __shfl_xor(a.x, m, 64);
        a.y += __shfl_xor(a.y, m, 64);
        a.z += __shfl_xor(a.z, m, 64);
        a.w += __shfl_xor(a.w, m, 64);
        b.x += __shfl_xor(b.x, m, 64);
        b.y += __shfl_xor(b.y, m, 64);
        b.z += __shfl_xor(b.z, m, 64);
        b.w += __shfl_xor(b.w, m, 64);
        kq  += __shfl_xor(kq,  m, 64);
    }

    // --- delta and out (out written by kgrp==0 lanes: 8x16B = 128B/wave) ---
    const f4 dlt = (vv - decay * a) * bta;
    if (kgrp == 0) {
        const f4 o = decay * b + kq * dlt;
        __builtin_nontemporal_store(o, (f4*)(out + (size_t)bh * DV + colf));
    }

    // --- rewrite state: S' = decay*S + k[r]*delta[v] (tile still in regs) ---
    #pragma unroll
    for (int i = 0; i < 16; ++i) {
        const float kv = ((const float*)kt)[i];
        const f4 w = decay * s[i] + kv * dlt;
        __builtin_nontemporal_store(w, (f4*)(So + (size_t)i * DV));
    }
}

extern "C" void kernel_launch(void* const* d_in, const int* in_sizes, int n_in,
                              void* d_out, int out_size, void* d_ws, size_t ws_size,
                              hipStream_t stream) {
    const float* q    = (const float*)d_in[0];
    const float* k    = (const float*)d_in[1];
    const float* v    = (const float*)d_in[2];
    const float* g    = (const float*)d_in[3];
    const float* beta = (const float*)d_in[4];
    const float* S    = (const float*)d_in[5];
    float* out = (float*)d_out;

    const int BH = in_sizes[3];   // g has B*H elements = 2048

    // BH blocks x 4 waves = BH*4 independent wave-tasks (one per v-slice)
    s1_cell_kernel<<<BH, 256, 0, stream>>>(q, k, v, g, beta, S, out, BH);
}